// Round 5
// baseline (391.872 us; speedup 1.0000x reference)
//
#include <hip/hip_runtime.h>
#include <math.h>

typedef unsigned short ushort_t;
typedef __attribute__((ext_vector_type(8))) short short8;   // 8 bf16 = 4 VGPR (MFMA A/B frag)
typedef __attribute__((ext_vector_type(4))) float f32x4;    // MFMA C/D frag
typedef __attribute__((ext_vector_type(4))) int int4v;
typedef __attribute__((ext_vector_type(4))) unsigned short ushort4v;

constexpr int S = 1024, D = 64, BH = 64;
constexpr int HALF = BH * S * D;          // imag offset in output
constexpr int KROW = 72;                  // bf16 row stride for K/Q tiles
constexpr int VROW = 40;                  // bf16 row stride for V^T / P tiles
constexpr int TILE_USH = 2 * 32 * KROW + 2 * 64 * VROW;  // 9728 ushorts = 19456 B per (bh,kb)
constexpr size_t WS_NEED = (size_t)BH * 32 * TILE_USH * 2;  // ~39.8 MB

#define MFMA16(a, b, c) __builtin_amdgcn_mfma_f32_16x16x32_bf16(a, b, c, 0, 0, 0)

__device__ __forceinline__ ushort_t f2bf(float f) {  // RNE fp32->bf16
  unsigned u = __float_as_uint(f);
  u += 0x7fff + ((u >> 16) & 1);
  return (ushort_t)(u >> 16);
}

__device__ __forceinline__ int4v pack8(float4 a, float4 b) {  // 8 fp32 -> 8 bf16 in 16B
  int4v r;
  r.x = (unsigned)f2bf(a.x) | ((unsigned)f2bf(a.y) << 16);
  r.y = (unsigned)f2bf(a.z) | ((unsigned)f2bf(a.w) << 16);
  r.z = (unsigned)f2bf(b.x) | ((unsigned)f2bf(b.y) << 16);
  r.w = (unsigned)f2bf(b.z) | ((unsigned)f2bf(b.w) << 16);
  return r;
}

#if defined(__has_builtin)
#if __has_builtin(__builtin_amdgcn_cvt_pk_bf16_f32)
#define HAS_CVT_PK_BF16 1
typedef __attribute__((ext_vector_type(2))) __bf16 bf16x2_t;
__device__ __forceinline__ unsigned cvtpk(float a, float b) {  // lo=bf16(a), hi=bf16(b)
  bf16x2_t v = __builtin_amdgcn_cvt_pk_bf16_f32(a, b);
  unsigned u;
  __builtin_memcpy(&u, &v, 4);
  return u;
}
#endif
#endif
#ifndef HAS_CVT_PK_BF16
#define HAS_CVT_PK_BF16 0
__device__ __forceinline__ unsigned cvtpk(float a, float b) {
  return (unsigned)f2bf(a) | ((unsigned)f2bf(b) << 16);
}
#endif

// ---------------- prepass: K,V -> bf16, V transposed via fp32 LDS (stride 65) ----------
__global__ __launch_bounds__(256)
void prepass_kernel(const float* __restrict__ kr, const float* __restrict__ ki,
                    const float* __restrict__ vr, const float* __restrict__ vi,
                    ushort_t* __restrict__ ws) {
  __shared__ float tmp2[32 * 65];                 // bank = (k + d) % 32 : 2-way free
  const int t = threadIdx.x;
  const int tile = blockIdx.x;                    // bh*32 + kb
  const size_t gbase = (size_t)tile * (32 * D);
  ushort_t* wst = ws + (size_t)tile * TILE_USH;
  const int k = t >> 3, d0 = (t & 7) * 8;
  const int dT = t >> 2, k0 = (t & 3) * 8;        // transpose-read identity

  {
    float4 a = *(const float4*)(kr + gbase + k * D + d0);
    float4 b = *(const float4*)(kr + gbase + k * D + d0 + 4);
    *(int4v*)(wst + k * KROW + d0) = pack8(a, b);
  }
  {
    float4 a = *(const float4*)(ki + gbase + k * D + d0);
    float4 b = *(const float4*)(ki + gbase + k * D + d0 + 4);
    *(int4v*)(wst + 2304 + k * KROW + d0) = pack8(a, b);
  }
  {
    float4 a = *(const float4*)(vr + gbase + k * D + d0);
    float4 b = *(const float4*)(vr + gbase + k * D + d0 + 4);
    *(float4*)&tmp2[k * 65 + d0] = a;
    *(float4*)&tmp2[k * 65 + d0 + 4] = b;
  }
  __syncthreads();
  {
    float4 a, b;
    a.x = tmp2[(k0 + 0) * 65 + dT]; a.y = tmp2[(k0 + 1) * 65 + dT];
    a.z = tmp2[(k0 + 2) * 65 + dT]; a.w = tmp2[(k0 + 3) * 65 + dT];
    b.x = tmp2[(k0 + 4) * 65 + dT]; b.y = tmp2[(k0 + 5) * 65 + dT];
    b.z = tmp2[(k0 + 6) * 65 + dT]; b.w = tmp2[(k0 + 7) * 65 + dT];
    *(int4v*)(wst + 4608 + dT * VROW + k0) = pack8(a, b);
  }
  __syncthreads();
  {
    float4 a = *(const float4*)(vi + gbase + k * D + d0);
    float4 b = *(const float4*)(vi + gbase + k * D + d0 + 4);
    *(float4*)&tmp2[k * 65 + d0] = a;
    *(float4*)&tmp2[k * 65 + d0 + 4] = b;
  }
  __syncthreads();
  {
    float4 a, b;
    a.x = tmp2[(k0 + 0) * 65 + dT]; a.y = tmp2[(k0 + 1) * 65 + dT];
    a.z = tmp2[(k0 + 2) * 65 + dT]; a.w = tmp2[(k0 + 3) * 65 + dT];
    b.x = tmp2[(k0 + 4) * 65 + dT]; b.y = tmp2[(k0 + 5) * 65 + dT];
    b.z = tmp2[(k0 + 6) * 65 + dT]; b.w = tmp2[(k0 + 7) * 65 + dT];
    *(int4v*)(wst + 4608 + 64 * VROW + dT * VROW + k0) = pack8(a, b);
  }
}

// ---------------- main MFMA kernel: 64 q-rows/block, 4 waves x 16 q-rows -------------------
// Depth-2 REGISTER prefetch: plain global loads are NOT drained at s_barrier (only
// LDS-destined DMA is) — each tile's loads get ~2 compute phases in flight, covering
// the ~900-cycle HBM latency that capped round 3.
__global__ __launch_bounds__(256, 3)
void cvattn_mfma(const float* __restrict__ gq_r, const float* __restrict__ gq_i,
                 const ushort_t* __restrict__ ws, float* __restrict__ gout) {
  // LDS (bytes): [0,19456) staged K/V tile; [19456,39936) per-wave P bufs / Q-stage overlay.
  __shared__ __attribute__((aligned(16))) char smem[39936];
  ushort_t* sB = (ushort_t*)smem;        // Kr@0, Ki@2304, Vtr@4608, Vti@7168 (ushort offs)
  ushort_t* sP = (ushort_t*)(smem + 19456);
  ushort_t* sQ = (ushort_t*)(smem + 19456);  // overlay: Qr[64][72], Qi after

  const int t = threadIdx.x;
  const int lane = t & 63, wave = t >> 6;
  const int m = lane & 15, quad = lane >> 4;
  const int qt = blockIdx.x, bh = blockIdx.y;
  const size_t base = (size_t)bh * (S * D);

  // ---- stage Q (fp32 -> bf16 LDS, once) ----
  {
    const float* qr = gq_r + base + (size_t)qt * (64 * D);
    const float* qi = gq_i + base + (size_t)qt * (64 * D);
#pragma unroll
    for (int i = 0; i < 4; ++i) {
      int e = (i * 256 + t) * 4;
      int q = e >> 6, d = e & 63;
      float4 a = *(const float4*)(qr + e);
      float4 b = *(const float4*)(qi + e);
      ushort4v wa = {f2bf(a.x), f2bf(a.y), f2bf(a.z), f2bf(a.w)};
      ushort4v wb = {f2bf(b.x), f2bf(b.y), f2bf(b.z), f2bf(b.w)};
      *(ushort4v*)&sQ[q * KROW + d] = wa;
      *(ushort4v*)&sQ[64 * KROW + q * KROW + d] = wb;
    }
  }
  __syncthreads();

  // ---- hoist Q A-frags (row m = q, k = quad*8+j) ----
  short8 fQr[2], fQi[2], fQin[2];
  {
    const int qrow = wave * 16 + m;
#pragma unroll
    for (int dc = 0; dc < 2; ++dc) {
      fQr[dc] = *(const short8*)&sQ[qrow * KROW + dc * 32 + quad * 8];
      fQi[dc] = *(const short8*)&sQ[64 * KROW + qrow * KROW + dc * 32 + quad * 8];
      fQin[dc] = fQi[dc] ^ (short)0x8000;  // -Qi (bf16 sign flip)
    }
  }

  f32x4 aAr[4] = {}, aAi[4] = {}, aUr[4] = {}, aUi[4] = {};
  float mn4[4] = {1e30f, 1e30f, 1e30f, 1e30f};   // track |s|^2 (sqrt at end)
  float mx4[4] = {0.f, 0.f, 0.f, 0.f};

  ushort_t* pw = sP + wave * 2560;  // pr@0, pi@640, ur@1280, ui@1920
  const ushort_t* wsrc = ws + (size_t)bh * 32 * TILE_USH;

  // ---- depth-2 register prefetch: preA holds even tiles, preB odd tiles ----
  int4v preA[5], preB[5];
#pragma unroll
  for (int i = 0; i < 5; ++i) {
    int idx = i * 256 + t;
    if (idx < 1216) preA[i] = *(const int4v*)(wsrc + idx * 8);            // tile 0
  }
#pragma unroll
  for (int i = 0; i < 5; ++i) {
    int idx = i * 256 + t;
    if (idx < 1216) preB[i] = *(const int4v*)(wsrc + TILE_USH + idx * 8); // tile 1
  }

#pragma unroll 2
  for (int kb = 0; kb < 32; ++kb) {
    const bool evenkb = (kb & 1) == 0;   // static under unroll 2
    __syncthreads();  // prev iter's LDS reads done (also covers Q-frag reads vs P overlay)
    // write tile kb to LDS from its register set (loads issued 2 iters ago)
#pragma unroll
    for (int i = 0; i < 5; ++i) {
      int idx = i * 256 + t;
      if (idx < 1216) *(int4v*)(smem + idx * 16) = evenkb ? preA[i] : preB[i];
    }
    // refill the freed set with tile kb+2 — two full compute phases in flight
    if (kb + 2 < 32) {
      const ushort_t* g = wsrc + (size_t)(kb + 2) * TILE_USH;
#pragma unroll
      for (int i = 0; i < 5; ++i) {
        int idx = i * 256 + t;
        if (idx < 1216) {
          if (evenkb) preA[i] = *(const int4v*)(g + idx * 8);
          else        preB[i] = *(const int4v*)(g + idx * 8);
        }
      }
    }
    __syncthreads();

    // ---- QK^T (complex) -> normalize -> P/U to LDS ----
#pragma unroll
    for (int ks = 0; ks < 2; ++ks) {
      const int krow = ks * 16 + m;
      short8 fKr0 = *(const short8*)&sB[krow * KROW + quad * 8];
      short8 fKr1 = *(const short8*)&sB[krow * KROW + 32 + quad * 8];
      short8 fKi0 = *(const short8*)&sB[2304 + krow * KROW + quad * 8];
      short8 fKi1 = *(const short8*)&sB[2304 + krow * KROW + 32 + quad * 8];
      f32x4 cSr = {}, cSi = {};
      cSr = MFMA16(fQr[0], fKr0, cSr);
      cSr = MFMA16(fQr[1], fKr1, cSr);
      cSr = MFMA16(fQin[0], fKi0, cSr);   // - Qi*Ki
      cSr = MFMA16(fQin[1], fKi1, cSr);
      cSi = MFMA16(fQr[0], fKi0, cSi);
      cSi = MFMA16(fQr[1], fKi1, cSi);
      cSi = MFMA16(fQi[0], fKr0, cSi);
      cSi = MFMA16(fQi[1], fKr1, cSi);
      // temperature /8 cancels in the min-max norm (scale-invariant)
      const int off0 = ks * 16 + m;
#pragma unroll
      for (int r = 0; r < 4; ++r) {
        float sr = cSr[r], si = cSi[r];
        float t2 = sr * sr + si * si;
        float rq = __builtin_amdgcn_rsqf(t2);
        mn4[r] = fminf(mn4[r], t2);
        mx4[r] = fmaxf(mx4[r], t2);
        const int off = (quad * 4 + r) * VROW + off0;
        unsigned ds = cvtpk(sr, si);            // packed RNE bf16 pair
        unsigned du = cvtpk(sr * rq, si * rq);  // unit phase pair
        pw[off]        = (ushort_t)ds;
        pw[640 + off]  = (ushort_t)(ds >> 16);
        pw[1280 + off] = (ushort_t)du;
        pw[1920 + off] = (ushort_t)(du >> 16);
      }
    }

    // ---- dual PV: A += s*v, U += u*v (complex) ----
    const int prow = m * VROW + quad * 8;
    short8 fPr = *(const short8*)&pw[prow];
    short8 fPi = *(const short8*)&pw[640 + prow];
    short8 fUr = *(const short8*)&pw[1280 + prow];
    short8 fUi = *(const short8*)&pw[1920 + prow];
#pragma unroll
    for (int dt = 0; dt < 4; ++dt) {
      const int drow = dt * 16 + m;
      short8 fVr = *(const short8*)&sB[4608 + drow * VROW + quad * 8];
      short8 fVi = *(const short8*)&sB[7168 + drow * VROW + quad * 8];
      short8 fVin = fVi ^ (short)0x8000;
      aAr[dt] = MFMA16(fPr, fVr, aAr[dt]);
      aAr[dt] = MFMA16(fPi, fVin, aAr[dt]);
      aAi[dt] = MFMA16(fPr, fVi, aAi[dt]);
      aAi[dt] = MFMA16(fPi, fVr, aAi[dt]);
      aUr[dt] = MFMA16(fUr, fVr, aUr[dt]);
      aUr[dt] = MFMA16(fUi, fVin, aUr[dt]);
      aUi[dt] = MFMA16(fUr, fVi, aUi[dt]);
      aUi[dt] = MFMA16(fUi, fVr, aUi[dt]);
    }
  }

  // ---- reduce mn/mx (of |s|^2) across the 16 lanes sharing each q-row ----
#pragma unroll
  for (int r = 0; r < 4; ++r) {
#pragma unroll
    for (int mask = 1; mask < 16; mask <<= 1) {
      mn4[r] = fminf(mn4[r], __shfl_xor(mn4[r], mask, 64));
      mx4[r] = fmaxf(mx4[r], __shfl_xor(mx4[r], mask, 64));
    }
  }
  float inv[4];
#pragma unroll
  for (int r = 0; r < 4; ++r) {
    mn4[r] = sqrtf(mn4[r]);
    mx4[r] = sqrtf(mx4[r]);
    inv[r] = 1.0f / (mx4[r] - mn4[r]);
  }

  // ---- epilogue: out = (A - mn*U) / (mx - mn) ----
  const int qbase = qt * 64 + wave * 16 + quad * 4;
#pragma unroll
  for (int dt = 0; dt < 4; ++dt) {
    const int d = dt * 16 + m;
#pragma unroll
    for (int r = 0; r < 4; ++r) {
      size_t o = base + (size_t)(qbase + r) * D + d;
      gout[o] = (aAr[dt][r] - mn4[r] * aUr[dt][r]) * inv[r];
      gout[HALF + o] = (aAi[dt][r] - mn4[r] * aUi[dt][r]) * inv[r];
    }
  }
}

// ---------------- fp32 fallback (used only if ws too small) ----------------
constexpr int QT = 32, KT = 32;
constexpr int DP = D + 4;
constexpr int KP = KT + 1;

#define CDOT4(SR, SI, AR, AI, BR, BI)                              \
  SR += AR.x*BR.x + AR.y*BR.y + AR.z*BR.z + AR.w*BR.w              \
      - AI.x*BI.x - AI.y*BI.y - AI.z*BI.z - AI.w*BI.w;             \
  SI += AR.x*BI.x + AR.y*BI.y + AR.z*BI.z + AR.w*BI.w              \
      + AI.x*BR.x + AI.y*BR.y + AI.z*BR.z + AI.w*BR.w;

__global__ __launch_bounds__(256, 2)
void cvattn_fallback(const float* __restrict__ gq_r, const float* __restrict__ gq_i,
                     const float* __restrict__ gk_r, const float* __restrict__ gk_i,
                     const float* __restrict__ gv_r, const float* __restrict__ gv_i,
                     float* __restrict__ gout) {
  __shared__ float qs_r[QT][DP], qs_i[QT][DP];
  __shared__ float ks_r[KT][DP], ks_i[KT][DP];
  __shared__ float vs_r[KT][DP], vs_i[KT][DP];
  __shared__ float sc_r[QT][KP], sc_i[QT][KP], sc_m[QT][KP];
  const int t = threadIdx.x;
  const int qt2 = blockIdx.x, bh = blockIdx.y;
  const size_t base = (size_t)bh * (S * D);
  {
    const float* qr_p = gq_r + base + (size_t)qt2 * QT * D;
    const float* qi_p = gq_i + base + (size_t)qt2 * QT * D;
#pragma unroll
    for (int i = 0; i < 2; ++i) {
      int e = (t + i * 256) * 4;
      int row = e >> 6, col = e & 63;
      *(float4*)&qs_r[row][col] = *(const float4*)(qr_p + e);
      *(float4*)&qs_i[row][col] = *(const float4*)(qi_p + e);
    }
  }
  const int q0 = (t >> 4) * 2, k0 = (t & 15) * 2;
  const int rB = t >> 3, dc = (t & 7) * 8;
  float Ar[8] = {}, Ai[8] = {}, Ur[8] = {}, Ui[8] = {};
  float mn = 3.4e38f, mx = 0.0f;
  for (int kb = 0; kb < S / KT; ++kb) {
    __syncthreads();
    {
      const float* kr_p = gk_r + base + (size_t)kb * KT * D;
      const float* ki_p = gk_i + base + (size_t)kb * KT * D;
      const float* vr_p = gv_r + base + (size_t)kb * KT * D;
      const float* vi_p = gv_i + base + (size_t)kb * KT * D;
#pragma unroll
      for (int i = 0; i < 2; ++i) {
        int e = (t + i * 256) * 4;
        int row = e >> 6, col = e & 63;
        *(float4*)&ks_r[row][col] = *(const float4*)(kr_p + e);
        *(float4*)&ks_i[row][col] = *(const float4*)(ki_p + e);
        *(float4*)&vs_r[row][col] = *(const float4*)(vr_p + e);
        *(float4*)&vs_i[row][col] = *(const float4*)(vi_p + e);
      }
    }
    __syncthreads();
    {
      float s00r=0.f,s00i=0.f,s01r=0.f,s01i=0.f;
      float s10r=0.f,s10i=0.f,s11r=0.f,s11i=0.f;
#pragma unroll
      for (int d = 0; d < D; d += 4) {
        float4 a0r = *(const float4*)&qs_r[q0  ][d];
        float4 a0i = *(const float4*)&qs_i[q0  ][d];
        float4 a1r = *(const float4*)&qs_r[q0+1][d];
        float4 a1i = *(const float4*)&qs_i[q0+1][d];
        float4 b0r = *(const float4*)&ks_r[k0  ][d];
        float4 b0i = *(const float4*)&ks_i[k0  ][d];
        float4 b1r = *(const float4*)&ks_r[k0+1][d];
        float4 b1i = *(const float4*)&ks_i[k0+1][d];
        CDOT4(s00r, s00i, a0r, a0i, b0r, b0i);
        CDOT4(s01r, s01i, a0r, a0i, b1r, b1i);
        CDOT4(s10r, s10i, a1r, a1i, b0r, b0i);
        CDOT4(s11r, s11i, a1r, a1i, b1r, b1i);
      }
      s00r *= 0.125f; s00i *= 0.125f; s01r *= 0.125f; s01i *= 0.125f;
      s10r *= 0.125f; s10i *= 0.125f; s11r *= 0.125f; s11i *= 0.125f;
      sc_r[q0  ][k0  ] = s00r; sc_i[q0  ][k0  ] = s00i;
      sc_m[q0  ][k0  ] = sqrtf(s00r*s00r + s00i*s00i);
      sc_r[q0  ][k0+1] = s01r; sc_i[q0  ][k0+1] = s01i;
      sc_m[q0  ][k0+1] = sqrtf(s01r*s01r + s01i*s01i);
      sc_r[q0+1][k0  ] = s10r; sc_i[q0+1][k0  ] = s10i;
      sc_m[q0+1][k0  ] = sqrtf(s10r*s10r + s10i*s10i);
      sc_r[q0+1][k0+1] = s11r; sc_i[q0+1][k0+1] = s11i;
      sc_m[q0+1][k0+1] = sqrtf(s11r*s11r + s11i*s11i);
    }
    __syncthreads();
#pragma unroll 8
    for (int k = 0; k < KT; ++k) {
      float sr = sc_r[rB][k], si = sc_i[rB][k], mg = sc_m[rB][k];
      mn = fminf(mn, mg); mx = fmaxf(mx, mg);
      float inv = 1.0f / mg;
      float ur = sr * inv, ui = si * inv;
      float vr[8], vi[8];
      *(float4*)&vr[0] = *(const float4*)&vs_r[k][dc];
      *(float4*)&vr[4] = *(const float4*)&vs_r[k][dc + 4];
      *(float4*)&vi[0] = *(const float4*)&vs_i[k][dc];
      *(float4*)&vi[4] = *(const float4*)&vs_i[k][dc + 4];
#pragma unroll
      for (int j = 0; j < 8; ++j) {
        Ar[j] += sr * vr[j] - si * vi[j];
        Ai[j] += sr * vi[j] + si * vr[j];
        Ur[j] += ur * vr[j] - ui * vi[j];
        Ui[j] += ur * vi[j] + ui * vr[j];
      }
    }
  }
  float invspan = 1.0f / (mx - mn);
  float outr[8], outi[8];
#pragma unroll
  for (int j = 0; j < 8; ++j) {
    outr[j] = (Ar[j] - mn * Ur[j]) * invspan;
    outi[j] = (Ai[j] - mn * Ui[j]) * invspan;
  }
  size_t o = base + (size_t)(qt2 * QT + rB) * D + dc;
  *(float4*)(gout + o)            = *(float4*)&outr[0];
  *(float4*)(gout + o + 4)        = *(float4*)&outr[4];
  *(float4*)(gout + HALF + o)     = *(float4*)&outi[0];
  *(float4*)(gout + HALF + o + 4) = *(float4*)&outi[4];
}

extern "C" void kernel_launch(void* const* d_in, const int* in_sizes, int n_in,
                              void* d_out, int out_size, void* d_ws, size_t ws_size,
                              hipStream_t stream) {
  if (ws_size >= WS_NEED) {
    prepass_kernel<<<dim3(BH * 32), 256, 0, stream>>>(
        (const float*)d_in[2], (const float*)d_in[3],
        (const float*)d_in[4], (const float*)d_in[5], (ushort_t*)d_ws);
    cvattn_mfma<<<dim3(S / 64, BH), 256, 0, stream>>>(
        (const float*)d_in[0], (const float*)d_in[1],
        (const ushort_t*)d_ws, (float*)d_out);
  } else {
    cvattn_fallback<<<dim3(S / QT, BH), 256, 0, stream>>>(
        (const float*)d_in[0], (const float*)d_in[1],
        (const float*)d_in[2], (const float*)d_in[3],
        (const float*)d_in[4], (const float*)d_in[5], (float*)d_out);
  }
}

// Round 6
// 258.033 us; speedup vs baseline: 1.5187x; 1.5187x over previous
//
#include <hip/hip_runtime.h>
#include <math.h>

typedef unsigned short ushort_t;
typedef __attribute__((ext_vector_type(8))) short short8;   // 8 bf16 = 4 VGPR (MFMA A/B frag)
typedef __attribute__((ext_vector_type(4))) float f32x4;    // MFMA C/D frag
typedef __attribute__((ext_vector_type(4))) int int4v;

constexpr int S = 1024, D = 64, BH = 64;
constexpr int HALF = BH * S * D;          // imag offset in output
constexpr int KROW = 72;                  // ush row stride, K tiles (rows=s, cols=d)
constexpr int VROW = 72;                  // ush row stride, interleaved V^T (rows=d, cols=k'=2s+c)
constexpr int TILE_USH = 2 * 32 * KROW + 64 * VROW;  // 4608 + 4608 = 9216 ush = 18432 B
constexpr int TILE_B = TILE_USH * 2;
constexpr size_t WS_NEED = (size_t)BH * 32 * TILE_B;  // 37.7 MB (< 39.8 MB, which fit before)

#define MFMA16(a, b, c) __builtin_amdgcn_mfma_f32_16x16x32_bf16(a, b, c, 0, 0, 0)

__device__ __forceinline__ ushort_t f2bf(float f) {  // RNE fp32->bf16
  unsigned u = __float_as_uint(f);
  u += 0x7fff + ((u >> 16) & 1);
  return (ushort_t)(u >> 16);
}

__device__ __forceinline__ int4v pack8(float4 a, float4 b) {  // 8 fp32 -> 8 bf16 in 16B
  int4v r;
  r.x = (unsigned)f2bf(a.x) | ((unsigned)f2bf(a.y) << 16);
  r.y = (unsigned)f2bf(a.z) | ((unsigned)f2bf(a.w) << 16);
  r.z = (unsigned)f2bf(b.x) | ((unsigned)f2bf(b.y) << 16);
  r.w = (unsigned)f2bf(b.z) | ((unsigned)f2bf(b.w) << 16);
  return r;
}

#if defined(__has_builtin)
#if __has_builtin(__builtin_amdgcn_cvt_pk_bf16_f32)
#define HAS_CVT_PK_BF16 1
typedef __attribute__((ext_vector_type(2))) __bf16 bf16x2_t;
__device__ __forceinline__ unsigned cvtpk(float a, float b) {  // lo=bf16(a), hi=bf16(b)
  bf16x2_t v = __builtin_amdgcn_cvt_pk_bf16_f32(a, b);
  unsigned u;
  __builtin_memcpy(&u, &v, 4);
  return u;
}
#endif
#endif
#ifndef HAS_CVT_PK_BF16
#define HAS_CVT_PK_BF16 0
__device__ __forceinline__ unsigned cvtpk(float a, float b) {
  return (unsigned)f2bf(a) | ((unsigned)f2bf(b) << 16);
}
#endif

// twist: per dword (lo=a, hi=b) -> (lo=-b, hi=a). Turns the (vr,-vi) layout into (vi,vr).
__device__ __forceinline__ short8 twist(short8 v) {
  int4v u;
  __builtin_memcpy(&u, &v, 16);
  int4v w;
  w.x = (int)((((unsigned)u.x >> 16) | ((unsigned)u.x << 16)) ^ 0x8000u);
  w.y = (int)((((unsigned)u.y >> 16) | ((unsigned)u.y << 16)) ^ 0x8000u);
  w.z = (int)((((unsigned)u.z >> 16) | ((unsigned)u.z << 16)) ^ 0x8000u);
  w.w = (int)((((unsigned)u.w >> 16) | ((unsigned)u.w << 16)) ^ 0x8000u);
  short8 r;
  __builtin_memcpy(&r, &w, 16);
  return r;
}

// ---------------- prepass: K classic bf16; V^T complex-interleaved (vr,-vi) --------------
__global__ __launch_bounds__(256)
void prepass_kernel(const float* __restrict__ kr, const float* __restrict__ ki,
                    const float* __restrict__ vr, const float* __restrict__ vi,
                    ushort_t* __restrict__ ws) {
  __shared__ float svr[32 * 65], svi[32 * 65];    // bank = (s + d) % 32 : 2-way free
  const int t = threadIdx.x;
  const int tile = blockIdx.x;                    // bh*32 + kb
  const size_t gbase = (size_t)tile * (32 * D);
  ushort_t* wst = ws + (size_t)tile * TILE_USH;
  const int k = t >> 3, d0 = (t & 7) * 8;
  const int dT = t >> 2, k0 = (t & 3) * 8;        // transpose-read identity

  {
    float4 a = *(const float4*)(kr + gbase + k * D + d0);
    float4 b = *(const float4*)(kr + gbase + k * D + d0 + 4);
    *(int4v*)(wst + k * KROW + d0) = pack8(a, b);
  }
  {
    float4 a = *(const float4*)(ki + gbase + k * D + d0);
    float4 b = *(const float4*)(ki + gbase + k * D + d0 + 4);
    *(int4v*)(wst + 2304 + k * KROW + d0) = pack8(a, b);
  }
  {
    float4 a = *(const float4*)(vr + gbase + k * D + d0);
    float4 b = *(const float4*)(vr + gbase + k * D + d0 + 4);
    *(float4*)&svr[k * 65 + d0] = a;
    *(float4*)&svr[k * 65 + d0 + 4] = b;
    float4 c = *(const float4*)(vi + gbase + k * D + d0);
    float4 d = *(const float4*)(vi + gbase + k * D + d0 + 4);
    *(float4*)&svi[k * 65 + d0] = c;
    *(float4*)&svi[k * 65 + d0 + 4] = d;
  }
  __syncthreads();
  {
    unsigned dws[8];
#pragma unroll
    for (int j = 0; j < 8; ++j) {
      int s = k0 + j;
      dws[j] = cvtpk(svr[s * 65 + dT], -svi[s * 65 + dT]);  // k'=2s: vr, k'=2s+1: -vi
    }
    ushort_t* dst = wst + 4608 + dT * VROW + 2 * k0;
    *(int4v*)dst = *(int4v*)&dws[0];
    *(int4v*)(dst + 8) = *(int4v*)&dws[4];
  }
}

// ---------------- main MFMA kernel: 128 q-rows/block (2 q-halves), 4 waves ----------------
// r3 skeleton (depth-1 branch-free register prefetch, 2 barriers/iter) + K/V frag reuse
// across 2 q-halves + complex-interleaved P/V (P writes b32, Vim derived in-register).
__global__ __launch_bounds__(256, 2)
void cvattn_mfma(const float* __restrict__ gq_r, const float* __restrict__ gq_i,
                 const ushort_t* __restrict__ ws, float* __restrict__ gout) {
  // LDS: [0,18432) staged tile (Kr@0, Ki@2304, Vre@4608 ush); [18432,55296) per-wave P/U.
  __shared__ __attribute__((aligned(16))) char smem[55296];
  ushort_t* sB = (ushort_t*)smem;
  const int t = threadIdx.x;
  const int lane = t & 63, wave = t >> 6;
  const int m = lane & 15, quad = lane >> 4;
  const int qt = blockIdx.x, bh = blockIdx.y;
  const size_t base = (size_t)bh * (S * D);

  // per-wave P/U region: [h][buf][16 q][36 dw]; p@0, u@576 dw; h1 @1152 dw
  unsigned* pwu = (unsigned*)(smem + 18432) + wave * 2304;

  // ---- Q fragments straight from global (one-time, uncoalesced-but-small) ----
  short8 fQr[2][2], fQi[2][2];  // [h][dc]
#pragma unroll
  for (int h = 0; h < 2; ++h) {
    const int row = qt * 128 + h * 64 + wave * 16 + m;
#pragma unroll
    for (int dc = 0; dc < 2; ++dc) {
      const int d = dc * 32 + quad * 8;
      const float* pr = gq_r + base + (size_t)row * D + d;
      const float* pi = gq_i + base + (size_t)row * D + d;
      int4v vr_ = pack8(*(const float4*)pr, *(const float4*)(pr + 4));
      int4v vi_ = pack8(*(const float4*)pi, *(const float4*)(pi + 4));
      __builtin_memcpy(&fQr[h][dc], &vr_, 16);
      __builtin_memcpy(&fQi[h][dc], &vi_, 16);
    }
  }

  f32x4 aAr[2][4] = {}, aAi[2][4] = {}, aUr[2][4] = {}, aUi[2][4] = {};
  float mn4[2][4], mx4[2][4];
#pragma unroll
  for (int h = 0; h < 2; ++h)
#pragma unroll
    for (int r = 0; r < 4; ++r) { mn4[h][r] = 1e30f; mx4[h][r] = 0.f; }

  const ushort_t* wsrc = ws + (size_t)bh * 32 * TILE_USH;

  // ---- depth-1 register prefetch (branch-free, r3-proven) ----
  int4v pre[5];
#pragma unroll
  for (int i = 0; i < 5; ++i) {
    int idx = i * 256 + t;
    if (idx < TILE_B / 16) pre[i] = *(const int4v*)(wsrc + idx * 8);
  }

  for (int kb = 0; kb < 32; ++kb) {
    __syncthreads();  // prev iter's LDS reads done
#pragma unroll
    for (int i = 0; i < 5; ++i) {
      int idx = i * 256 + t;
      if (idx < TILE_B / 16) *(int4v*)(smem + idx * 16) = pre[i];
    }
    if (kb + 1 < 32) {
      const ushort_t* g = wsrc + (size_t)(kb + 1) * TILE_USH;
#pragma unroll
      for (int i = 0; i < 5; ++i) {
        int idx = i * 256 + t;
        if (idx < TILE_B / 16) pre[i] = *(const int4v*)(g + idx * 8);
      }
    }
    __syncthreads();

    // ---- QK^T (complex) -> normalize -> interleaved (re,im) b32 P/U writes ----
#pragma unroll
    for (int ks = 0; ks < 2; ++ks) {
      const int krow = ks * 16 + m;
      short8 fKr0 = *(const short8*)&sB[krow * KROW + quad * 8];
      short8 fKr1 = *(const short8*)&sB[krow * KROW + 32 + quad * 8];
      short8 fKi0 = *(const short8*)&sB[2304 + krow * KROW + quad * 8];
      short8 fKi1 = *(const short8*)&sB[2304 + krow * KROW + 32 + quad * 8];
      short8 fKn0 = fKi0 ^ (short)0x8000;   // -Ki (shared by both q-halves)
      short8 fKn1 = fKi1 ^ (short)0x8000;
#pragma unroll
      for (int h = 0; h < 2; ++h) {
        f32x4 cSr = {}, cSi = {};
        cSr = MFMA16(fQr[h][0], fKr0, cSr);
        cSr = MFMA16(fQr[h][1], fKr1, cSr);
        cSr = MFMA16(fQi[h][0], fKn0, cSr);
        cSr = MFMA16(fQi[h][1], fKn1, cSr);
        cSi = MFMA16(fQr[h][0], fKi0, cSi);
        cSi = MFMA16(fQr[h][1], fKi1, cSi);
        cSi = MFMA16(fQi[h][0], fKr0, cSi);
        cSi = MFMA16(fQi[h][1], fKr1, cSi);
        // temperature /8 cancels in the min-max norm (scale-invariant)
#pragma unroll
        for (int r = 0; r < 4; ++r) {
          float sr = cSr[r], si = cSi[r];
          float t2 = sr * sr + si * si;
          float rq = __builtin_amdgcn_rsqf(t2);
          mn4[h][r] = fminf(mn4[h][r], t2);
          mx4[h][r] = fmaxf(mx4[h][r], t2);
          const int dwo = h * 1152 + (quad * 4 + r) * 36 + ks * 16 + m;
          pwu[dwo] = cvtpk(sr, si);              // P: k'=2s -> re, 2s+1 -> im
          pwu[576 + dwo] = cvtpk(sr * rq, si * rq);  // U: unit phase
        }
      }
    }

    // ---- dual PV via interleaved MFMAs: acc += Pc . Vtwist ----
    short8 fP0[2], fP1[2], fU0[2], fU1[2];
#pragma unroll
    for (int h = 0; h < 2; ++h) {
      const int bo = h * 1152 + m * 36 + quad * 4;
      fP0[h] = *(const short8*)&pwu[bo];
      fP1[h] = *(const short8*)&pwu[bo + 16];
      fU0[h] = *(const short8*)&pwu[576 + bo];
      fU1[h] = *(const short8*)&pwu[576 + bo + 16];
    }
#pragma unroll
    for (int dt = 0; dt < 4; ++dt) {
      const unsigned* vrow = (const unsigned*)sB + 2304 + (dt * 16 + m) * 36 + quad * 4;
      short8 vre0 = *(const short8*)vrow;         // (vr,-vi) interleaved, k'=quad*8..
      short8 vre1 = *(const short8*)(vrow + 16);  // k' + 32
      short8 vim0 = twist(vre0);                  // (vi, vr)
      short8 vim1 = twist(vre1);
#pragma unroll
      for (int h = 0; h < 2; ++h) {
        aAr[h][dt] = MFMA16(fP0[h], vre0, aAr[h][dt]);
        aAr[h][dt] = MFMA16(fP1[h], vre1, aAr[h][dt]);
        aAi[h][dt] = MFMA16(fP0[h], vim0, aAi[h][dt]);
        aAi[h][dt] = MFMA16(fP1[h], vim1, aAi[h][dt]);
        aUr[h][dt] = MFMA16(fU0[h], vre0, aUr[h][dt]);
        aUr[h][dt] = MFMA16(fU1[h], vre1, aUr[h][dt]);
        aUi[h][dt] = MFMA16(fU0[h], vim0, aUi[h][dt]);
        aUi[h][dt] = MFMA16(fU1[h], vim1, aUi[h][dt]);
      }
    }
  }

  // ---- reduce mn/mx (of |s|^2) across the 16 lanes sharing each q-row; epilogue ----
#pragma unroll
  for (int h = 0; h < 2; ++h) {
    float inv[4];
#pragma unroll
    for (int r = 0; r < 4; ++r) {
#pragma unroll
      for (int mask = 1; mask < 16; mask <<= 1) {
        mn4[h][r] = fminf(mn4[h][r], __shfl_xor(mn4[h][r], mask, 64));
        mx4[h][r] = fmaxf(mx4[h][r], __shfl_xor(mx4[h][r], mask, 64));
      }
      mn4[h][r] = sqrtf(mn4[h][r]);
      mx4[h][r] = sqrtf(mx4[h][r]);
      inv[r] = 1.0f / (mx4[h][r] - mn4[h][r]);
    }
    const int qbase = qt * 128 + h * 64 + wave * 16 + quad * 4;
#pragma unroll
    for (int dt = 0; dt < 4; ++dt) {
      const int d = dt * 16 + m;
#pragma unroll
      for (int r = 0; r < 4; ++r) {
        size_t o = base + (size_t)(qbase + r) * D + d;
        gout[o] = (aAr[h][dt][r] - mn4[h][r] * aUr[h][dt][r]) * inv[r];
        gout[HALF + o] = (aAi[h][dt][r] - mn4[h][r] * aUi[h][dt][r]) * inv[r];
      }
    }
  }
}

// ---------------- fp32 fallback (used only if ws too small) ----------------
constexpr int QT = 32, KT = 32;
constexpr int DP = D + 4;
constexpr int KP = KT + 1;

#define CDOT4(SR, SI, AR, AI, BR, BI)                              \
  SR += AR.x*BR.x + AR.y*BR.y + AR.z*BR.z + AR.w*BR.w              \
      - AI.x*BI.x - AI.y*BI.y - AI.z*BI.z - AI.w*BI.w;             \
  SI += AR.x*BI.x + AR.y*BI.y + AR.z*BI.z + AR.w*BI.w              \
      + AI.x*BR.x + AI.y*BR.y + AI.z*BR.z + AI.w*BR.w;

__global__ __launch_bounds__(256, 2)
void cvattn_fallback(const float* __restrict__ gq_r, const float* __restrict__ gq_i,
                     const float* __restrict__ gk_r, const float* __restrict__ gk_i,
                     const float* __restrict__ gv_r, const float* __restrict__ gv_i,
                     float* __restrict__ gout) {
  __shared__ float qs_r[QT][DP], qs_i[QT][DP];
  __shared__ float ks_r[KT][DP], ks_i[KT][DP];
  __shared__ float vs_r[KT][DP], vs_i[KT][DP];
  __shared__ float sc_r[QT][KP], sc_i[QT][KP], sc_m[QT][KP];
  const int t = threadIdx.x;
  const int qt2 = blockIdx.x, bh = blockIdx.y;
  const size_t base = (size_t)bh * (S * D);
  {
    const float* qr_p = gq_r + base + (size_t)qt2 * QT * D;
    const float* qi_p = gq_i + base + (size_t)qt2 * QT * D;
#pragma unroll
    for (int i = 0; i < 2; ++i) {
      int e = (t + i * 256) * 4;
      int row = e >> 6, col = e & 63;
      *(float4*)&qs_r[row][col] = *(const float4*)(qr_p + e);
      *(float4*)&qs_i[row][col] = *(const float4*)(qi_p + e);
    }
  }
  const int q0 = (t >> 4) * 2, k0 = (t & 15) * 2;
  const int rB = t >> 3, dc = (t & 7) * 8;
  float Ar[8] = {}, Ai[8] = {}, Ur[8] = {}, Ui[8] = {};
  float mn = 3.4e38f, mx = 0.0f;
  for (int kb = 0; kb < S / KT; ++kb) {
    __syncthreads();
    {
      const float* kr_p = gk_r + base + (size_t)kb * KT * D;
      const float* ki_p = gk_i + base + (size_t)kb * KT * D;
      const float* vr_p = gv_r + base + (size_t)kb * KT * D;
      const float* vi_p = gv_i + base + (size_t)kb * KT * D;
#pragma unroll
      for (int i = 0; i < 2; ++i) {
        int e = (t + i * 256) * 4;
        int row = e >> 6, col = e & 63;
        *(float4*)&ks_r[row][col] = *(const float4*)(kr_p + e);
        *(float4*)&ks_i[row][col] = *(const float4*)(ki_p + e);
        *(float4*)&vs_r[row][col] = *(const float4*)(vr_p + e);
        *(float4*)&vs_i[row][col] = *(const float4*)(vi_p + e);
      }
    }
    __syncthreads();
    {
      float s00r=0.f,s00i=0.f,s01r=0.f,s01i=0.f;
      float s10r=0.f,s10i=0.f,s11r=0.f,s11i=0.f;
#pragma unroll
      for (int d = 0; d < D; d += 4) {
        float4 a0r = *(const float4*)&qs_r[q0  ][d];
        float4 a0i = *(const float4*)&qs_i[q0  ][d];
        float4 a1r = *(const float4*)&qs_r[q0+1][d];
        float4 a1i = *(const float4*)&qs_i[q0+1][d];
        float4 b0r = *(const float4*)&ks_r[k0  ][d];
        float4 b0i = *(const float4*)&ks_i[k0  ][d];
        float4 b1r = *(const float4*)&ks_r[k0+1][d];
        float4 b1i = *(const float4*)&ks_i[k0+1][d];
        CDOT4(s00r, s00i, a0r, a0i, b0r, b0i);
        CDOT4(s01r, s01i, a0r, a0i, b1r, b1i);
        CDOT4(s10r, s10i, a1r, a1i, b0r, b0i);
        CDOT4(s11r, s11i, a1r, a1i, b1r, b1i);
      }
      s00r *= 0.125f; s00i *= 0.125f; s01r *= 0.125f; s01i *= 0.125f;
      s10r *= 0.125f; s10i *= 0.125f; s11r *= 0.125f; s11i *= 0.125f;
      sc_r[q0  ][k0  ] = s00r; sc_i[q0  ][k0  ] = s00i;
      sc_m[q0  ][k0  ] = sqrtf(s00r*s00r + s00i*s00i);
      sc_r[q0  ][k0+1] = s01r; sc_i[q0  ][k0+1] = s01i;
      sc_m[q0  ][k0+1] = sqrtf(s01r*s01r + s01i*s01i);
      sc_r[q0+1][k0  ] = s10r; sc_i[q0+1][k0  ] = s10i;
      sc_m[q0+1][k0  ] = sqrtf(s10r*s10r + s10i*s10i);
      sc_r[q0+1][k0+1] = s11r; sc_i[q0+1][k0+1] = s11i;
      sc_m[q0+1][k0+1] = sqrtf(s11r*s11r + s11i*s11i);
    }
    __syncthreads();
#pragma unroll 8
    for (int k = 0; k < KT; ++k) {
      float sr = sc_r[rB][k], si = sc_i[rB][k], mg = sc_m[rB][k];
      mn = fminf(mn, mg); mx = fmaxf(mx, mg);
      float inv = 1.0f / mg;
      float ur = sr * inv, ui = si * inv;
      float vr[8], vi[8];
      *(float4*)&vr[0] = *(const float4*)&vs_r[k][dc];
      *(float4*)&vr[4] = *(const float4*)&vs_r[k][dc + 4];
      *(float4*)&vi[0] = *(const float4*)&vs_i[k][dc];
      *(float4*)&vi[4] = *(const float4*)&vs_i[k][dc + 4];
#pragma unroll
      for (int j = 0; j < 8; ++j) {
        Ar[j] += sr * vr[j] - si * vi[j];
        Ai[j] += sr * vi[j] + si * vr[j];
        Ur[j] += ur * vr[j] - ui * vi[j];
        Ui[j] += ur * vi[j] + ui * vr[j];
      }
    }
  }
  float invspan = 1.0f / (mx - mn);
  float outr[8], outi[8];
#pragma unroll
  for (int j = 0; j < 8; ++j) {
    outr[j] = (Ar[j] - mn * Ur[j]) * invspan;
    outi[j] = (Ai[j] - mn * Ui[j]) * invspan;
  }
  size_t o = base + (size_t)(qt2 * QT + rB) * D + dc;
  *(float4*)(gout + o)            = *(float4*)&outr[0];
  *(float4*)(gout + o + 4)        = *(float4*)&outr[4];
  *(float4*)(gout + HALF + o)     = *(float4*)&outi[0];
  *(float4*)(gout + HALF + o + 4) = *(float4*)&outi[4];
}

extern "C" void kernel_launch(void* const* d_in, const int* in_sizes, int n_in,
                              void* d_out, int out_size, void* d_ws, size_t ws_size,
                              hipStream_t stream) {
  if (ws_size >= WS_NEED) {
    prepass_kernel<<<dim3(BH * 32), 256, 0, stream>>>(
        (const float*)d_in[2], (const float*)d_in[3],
        (const float*)d_in[4], (const float*)d_in[5], (ushort_t*)d_ws);
    cvattn_mfma<<<dim3(S / 128, BH), 256, 0, stream>>>(
        (const float*)d_in[0], (const float*)d_in[1],
        (const ushort_t*)d_ws, (float*)d_out);
  } else {
    cvattn_fallback<<<dim3(S / QT, BH), 256, 0, stream>>>(
        (const float*)d_in[0], (const float*)d_in[1],
        (const float*)d_in[2], (const float*)d_in[3],
        (const float*)d_in[4], (const float*)d_in[5], (float*)d_out);
  }
}